// Round 8
// baseline (411.291 us; speedup 1.0000x reference)
//
#include <hip/hip_runtime.h>
#include <array>

typedef __attribute__((ext_vector_type(8))) short short8;
typedef __attribute__((ext_vector_type(4))) float f32x4;
typedef __attribute__((ext_vector_type(4))) unsigned u32x4;

#define N_PATHS 19
#define SROW 148            // slab row stride (floats)

// ---- compile-time path tables ----
constexpr int kPL1[N_PATHS]  = {0,0,0,1,1,1,1,1,1,1,2,2,2,2,2,2,2,2,2};
constexpr int kPL2[N_PATHS]  = {0,1,2,0,1,1,1,2,2,2,0,1,1,1,2,2,2,2,2};
constexpr int kPL3[N_PATHS]  = {0,1,2,1,0,1,2,1,2,3,2,1,2,3,0,1,2,3,4};
constexpr int kIOFF[3]  = {0,1,4};
constexpr int kSP[5][6] = {{0,4,14,0,0,0},{1,3,5,7,11,15},{2,6,8,10,12,16},{9,13,17,0,0,0},{18,0,0,0,0,0}};
constexpr int kKS[5] = {3,6,6,3,1};
constexpr int kNT[5] = {4,4,4,2,1};
constexpr int kOB[5] = {0,64,256,576,800};
constexpr int kFB[5] = {0,12,36,60,66};
#define N_FRAGS 67

// ================= constexpr Wigner tables (r2-validated math) ==========
struct ccplx { double re, im; };
constexpr ccplx cmulc(ccplx a, ccplx b){ return {a.re*b.re - a.im*b.im, a.re*b.im + a.im*b.re}; }
constexpr double cfact(int n){ double f = 1.0; for (int i = 2; i <= n; ++i) f *= i; return f; }
constexpr double csqrt(double x){
  if (x <= 0.0) return 0.0;
  double g = x > 1.0 ? x : 1.0;
  for (int i = 0; i < 64; ++i) g = 0.5*(g + x/g);
  return g;
}
constexpr double c_su2cg(int j1,int j2,int j3,int m1,int m2){
  int m3 = m1+m2;
  int am3 = m3 < 0 ? -m3 : m3;
  int dj = j1-j2 < 0 ? j2-j1 : j1-j2;
  if (j3 < dj || j3 > j1+j2 || am3 > j3) return 0.0;
  double pref = (2.0*j3+1.0)*cfact(j3+j1-j2)*cfact(j3-j1+j2)*cfact(j1+j2-j3)/cfact(j1+j2+j3+1);
  pref = csqrt(pref);
  pref *= csqrt(cfact(j3+m3)*cfact(j3-m3)*cfact(j1-m1)*cfact(j1+m1)*cfact(j2-m2)*cfact(j2+m2));
  double s = 0.0;
  for (int k = 0; k <= j1+j2-j3; ++k){
    int a1=j1+j2-j3-k, a2=j1-m1-k, a3=j2+m2-k, a4=j3-j2+m1+k, a5=j3-j1-m2+k;
    if (a1<0||a2<0||a3<0||a4<0||a5<0) continue;
    double d = cfact(k)*cfact(a1)*cfact(a2)*cfact(a3)*cfact(a4)*cfact(a5);
    s += ((k&1) ? -1.0 : 1.0)/d;
  }
  return pref*s;
}
// q(l)[r][c] incl. (-i)^l rotation (l=1:-i, l=2:-1, l=3:+i)
constexpr ccplx qel(int l, int r, int c){
  const double rt = 0.70710678118654752440;
  int m = r - l;
  ccplx v{0.0, 0.0};
  if (m < 0){
    if (c == l - m) v = {rt, 0.0};
    else if (c == l + m) v = {0.0, -rt};
  } else if (m == 0){
    if (c == l) v = {1.0, 0.0};
  } else {
    double s = (m & 1) ? -1.0 : 1.0;
    if (c == l + m) v = {s*rt, 0.0};
    else if (c == l - m) v = {0.0, s*rt};
  }
  int ph = l & 3;
  if (ph == 1) return { v.im, -v.re};
  if (ph == 2) return {-v.re, -v.im};
  if (ph == 3) return {-v.im,  v.re};
  return v;
}
template<int P>
constexpr auto make_cg(){
  constexpr int l1 = kPL1[P], l2 = kPL2[P], l3 = kPL3[P];
  constexpr int D1 = 2*l1+1, D2v = 2*l2+1, D3 = 2*l3+1;
  double su[D1][D2v] = {};
  for (int i = 0; i < D1; ++i)
    for (int j = 0; j < D2v; ++j)
      su[i][j] = c_su2cg(l1, l2, l3, i-l1, j-l2);
  std::array<double, (size_t)D1*D2v*D3> re{}, im{};
  double sre = 0.0, sim = 0.0;
  for (int a = 0; a < D1; ++a)
    for (int b = 0; b < D2v; ++b)
      for (int c = 0; c < D3; ++c){
        ccplx acc{0.0, 0.0};
        for (int i = 0; i < D1; ++i)
          for (int j = 0; j < D2v; ++j){
            int kk = l3 + (i-l1) + (j-l2);
            if (kk < 0 || kk >= D3) continue;
            double cgv = su[i][j];
            if (cgv == 0.0) continue;
            ccplx q3 = qel(l3, c, kk);
            ccplx pr = cmulc(cmulc(qel(l1,a,i), qel(l2,b,j)), ccplx{q3.re, -q3.im});
            acc.re += pr.re*cgv; acc.im += pr.im*cgv;
          }
        size_t e = ((size_t)a*D2v + b)*D3 + c;
        re[e] = acc.re; im[e] = acc.im;
        sre += acc.re < 0 ? -acc.re : acc.re;
        sim += acc.im < 0 ? -acc.im : acc.im;
      }
  std::array<float, (size_t)D1*D2v*D3> out{};
  const bool useRe = (sre >= sim);
  const double norm = 1.0/csqrt((double)D3);
  for (size_t e = 0; e < out.size(); ++e){
    double v = (useRe ? re[e] : im[e])*norm;
    if (v < 1e-10 && v > -1e-10) v = 0.0;
    out[e] = (float)v;
  }
  return out;
}
template<int P> struct CGTab { static constexpr auto tab = make_cg<P>(); };
template<int P, int K> constexpr bool row_any(int E){
  for (int k = 0; k < K; ++k) if (CGTab<P>::tab[(size_t)E*K + k] != 0.0f) return true;
  return false;
}

__device__ inline unsigned short f2bf(float v){  // RNE fp32->bf16
  unsigned u = __builtin_bit_cast(unsigned, v);
  unsigned r = u + 0x7FFFu + ((u>>16)&1u);
  return (unsigned short)(r>>16);
}

// ---------------- W -> fragment-ordered bf16 (scale folded) ----------------
__global__ void prep_w_kernel(const float* __restrict__ W0, const float* __restrict__ W1,
                              const float* __restrict__ W2, const float* __restrict__ W3,
                              const float* __restrict__ W4, unsigned short* __restrict__ wout){
  int el = blockIdx.x*256 + threadIdx.x;
  if (el >= N_FRAGS*512) return;
  int frag = el>>9, r = el&511, lam = r>>3, j = r&7;
  int l  = (frag<12)?0 : (frag<36)?1 : (frag<60)?2 : (frag<66)?3 : 4;
  int fb = (l==0)?0 : (l==1)?12 : (l==2)?36 : (l==3)?60 : 66;
  int Ks = (l==0)?3 : (l==1)?6 : (l==2)?6 : (l==3)?3 : 1;
  int U  = (l==0)?96 : (l==1)?192 : (l==2)?192 : (l==3)?96 : 32;
  int rel = frag - fb, nt = rel/Ks, tt = rel - nt*Ks;
  int o = nt*16 + (lam&15);
  int u = tt*32 + (lam>>4)*8 + j;
  const float* W = (l==0)?W0 : (l==1)?W1 : (l==2)?W2 : (l==3)?W3 : W4;
  float scale = (l==0||l==3) ? 0.10206207261596575f
              : (l==4)       ? 0.17677669529663687f
                             : 0.07216878364870323f;
  wout[el] = f2bf(W[o*U + u] * scale);
}

// ---------------- main kernel ----------------
// Block = 128 thr = 2 waves, 16 samples; wave0: groups {0,1,3}, wave1: {2,4}.
// No barriers, no input LDS: each lane loads its own 288B spans global->reg
// (contiguous per build, L1/L2-served re-reads; both waves share the lines).
// A-frag (m89-validated): lane(s=lane&15,g=lane>>4), elem j -> TP(sample s, mul g*8+j).
// CG coefficients are instruction immediates via constexpr tables.

template<int P, int K, int E, int KK>
struct CKk {
  static __device__ __forceinline__ void run(float (&a0)[K], float (&a1)[K], float p0, float p1){
    constexpr float w = CGTab<P>::tab[(size_t)E*K + KK];
    if constexpr (w != 0.0f){
      a0[KK] = __builtin_fmaf(w, p0, a0[KK]);
      a1[KK] = __builtin_fmaf(w, p1, a1[KK]);
    }
    if constexpr (KK+1 < K) CKk<P,K,E,KK+1>::run(a0, a1, p0, p1);
  }
};

template<int P, int K, int D2v, int O1, int O2, int E, int NE>
struct CElem {
  static __device__ __forceinline__ void run(float (&a0)[K], float (&a1)[K],
                                             const float* xa, const float* xb){
    if constexpr (row_any<P,K>(E)){
      constexpr int i = E / D2v, jj = E - i*D2v;
      float p0 = xa[O1+i] * xb[O2+jj];
      float p1 = xa[9+O1+i] * xb[9+O2+jj];
      CKk<P,K,E,0>::run(a0, a1, p0, p1);
    }
    if constexpr (E+1 < NE) CElem<P,K,D2v,O1,O2,E+1,NE>::run(a0, a1, xa, xb);
  }
};

template<int L, int TT>
struct Slot {
  static constexpr int P  = kSP[L][TT];
  static constexpr int L1 = kPL1[P], L2_ = kPL2[P];
  static constexpr int D1 = 2*L1+1, D2v = 2*L2_+1;
  static constexpr int O1 = kIOFF[L1], O2 = kIOFF[L2_];
  static __device__ __forceinline__ void build(u32x4 (*af)[kKS[L]], const float* xa,
                                               const float* xb, int jp){
    constexpr int K = 2*L+1;
    float a0[K], a1[K];
    #pragma unroll
    for (int k=0;k<K;++k){ a0[k]=0.f; a1[k]=0.f; }
    CElem<P,K,D2v,O1,O2,0,D1*D2v>::run(a0, a1, xa, xb);
    #pragma unroll
    for (int k=0;k<K;++k){
      unsigned pk;
      asm("v_cvt_pk_bf16_f32 %0, %1, %2" : "=v"(pk) : "v"(a0[k]), "v"(a1[k]));
      af[k][TT][jp] = pk;        // lo16 = j even, hi16 = j odd
    }
    if constexpr (TT+1 < kKS[L]) Slot<L, TT+1>::build(af, xa, xb, jp);
  }
};

template<int L>
__device__ __forceinline__ void do_group(const float* __restrict__ x1g,
                                         const float* __restrict__ x2g, bool act,
                                         const short* __restrict__ wfrag,
                                         float* slab, float* __restrict__ out,
                                         int nrowb, int N, int lane){
  constexpr int K = 2*L+1, Ks = kKS[L], Nt = kNT[L];
  const int s = lane&15, g = lane>>4;
  u32x4 af[K][Ks];

  // ---- build all A-frags for this group from global inputs (CG = immediates) ----
  #pragma unroll
  for (int jp=0; jp<4; ++jp){
    float xa[18], xb[18];
    #pragma unroll
    for (int e=0; e<9; ++e){
      float2 va = {0.f,0.f}, vb = {0.f,0.f};
      if (act){
        va = *reinterpret_cast<const float2*>(x1g + jp*18 + e*2);  // 8B-aligned
        vb = *reinterpret_cast<const float2*>(x2g + jp*18 + e*2);
      }
      xa[e*2] = va.x; xa[e*2+1] = va.y;
      xb[e*2] = vb.x; xb[e*2+1] = vb.y;
    }
    Slot<L,0>::build(af, xa, xb, jp);
  }

  // ---- MFMA + per-nt stage/flush; B-frags double-buffered ----
  const short* wf = wfrag + (size_t)kFB[L]*512 + (size_t)lane*8;
  short8 bfc[Ks], bfn[Ks];
  #pragma unroll
  for (int tt=0; tt<Ks; ++tt)
    bfc[tt] = *reinterpret_cast<const short8*>(wf + tt*512);
  #pragma unroll
  for (int nt=0; nt<Nt; ++nt){
    if (nt+1 < Nt){
      #pragma unroll
      for (int tt=0; tt<Ks; ++tt)
        bfn[tt] = *reinterpret_cast<const short8*>(wf + ((nt+1)*Ks+tt)*512);
    }
    f32x4 acc[K];
    #pragma unroll
    for (int k=0;k<K;++k) acc[k] = (f32x4){0.f,0.f,0.f,0.f};
    #pragma unroll
    for (int tt=0; tt<Ks; ++tt)
      #pragma unroll
      for (int k=0;k<K;++k)
        acc[k] = __builtin_amdgcn_mfma_f32_16x16x32_bf16(
                   __builtin_bit_cast(short8, af[k][tt]), bfc[tt], acc[k], 0, 0, 0);
    // D-frag: row = sample g*4+r, col = o = nt*16+s  [m89 layout]
    #pragma unroll
    for (int k=0;k<K;++k)
      #pragma unroll
      for (int r=0;r<4;++r)
        slab[(g*4+r)*SROW + s*K + k] = acc[k][r];
    // flush this nt: 16 samples x (16 o x K) floats, full-64B-line float4 stores
    const int rr = lane>>2, q4 = lane&3;
    const float* sp = slab + rr*SROW;
    const bool on = (nrowb + rr) < N;
    float* op = out + (size_t)(nrowb+rr)*944 + kOB[L] + nt*16*K;
    #pragma unroll
    for (int c=0;c<K;++c){
      float4 v = *reinterpret_cast<const float4*>(sp + (c*4+q4)*4);
      if (on) *reinterpret_cast<float4*>(op + (c*4+q4)*4) = v;
    }
    if (nt+1 < Nt){
      #pragma unroll
      for (int tt=0; tt<Ks; ++tt) bfc[tt] = bfn[tt];
    }
  }
}

__global__ __launch_bounds__(128, 4) void tp_main(
    const float* __restrict__ x1, const float* __restrict__ x2,
    const short* __restrict__ wfrag, float* __restrict__ out, int N)
{
  __shared__ __align__(16) float stage[2*16*SROW];
  const int t = threadIdx.x, w = t>>6, lane = t&63;
  const int nb = blockIdx.x*16;
  const int s = lane&15, g = lane>>4;
  const int n = nb + s;
  const bool act = n < N;
  const size_t nbeg = (size_t)(act ? n : 0)*288 + g*72;
  const float* x1g = x1 + nbeg;
  const float* x2g = x2 + nbeg;
  float* slab = &stage[w*16*SROW];

  if (w == 0){
    do_group<0>(x1g, x2g, act, wfrag, slab, out, nb, N, lane);
    do_group<1>(x1g, x2g, act, wfrag, slab, out, nb, N, lane);
    do_group<3>(x1g, x2g, act, wfrag, slab, out, nb, N, lane);
  } else {
    do_group<2>(x1g, x2g, act, wfrag, slab, out, nb, N, lane);
    do_group<4>(x1g, x2g, act, wfrag, slab, out, nb, N, lane);
  }
}

extern "C" void kernel_launch(void* const* d_in, const int* in_sizes, int n_in,
                              void* d_out, int out_size, void* d_ws, size_t ws_size,
                              hipStream_t stream)
{
  (void)n_in; (void)out_size; (void)ws_size;
  const float* x1 = (const float*)d_in[0];
  const float* x2 = (const float*)d_in[1];
  const float* W0 = (const float*)d_in[2];
  const float* W1 = (const float*)d_in[3];
  const float* W2 = (const float*)d_in[4];
  const float* W3 = (const float*)d_in[5];
  const float* W4 = (const float*)d_in[6];
  float* out = (float*)d_out;
  int N = in_sizes[0] / 288;

  prep_w_kernel<<<dim3((N_FRAGS*512 + 255)/256), dim3(256), 0, stream>>>(
      W0, W1, W2, W3, W4, (unsigned short*)d_ws);
  int grid = (N + 15) / 16;
  tp_main<<<dim3(grid), dim3(128), 0, stream>>>(
      x1, x2, (const short*)d_ws, out, N);
}

// Round 9
// 380.497 us; speedup vs baseline: 1.0809x; 1.0809x over previous
//
#include <hip/hip_runtime.h>
#include <hip/hip_fp16.h>
#include <array>

typedef __attribute__((ext_vector_type(8))) short short8;
typedef __attribute__((ext_vector_type(4))) float f32x4;
typedef __attribute__((ext_vector_type(4))) unsigned u32x4;

#define N_PATHS 19
#define HROW 290            // input LDS row stride in halves (580B; 145 dw -> 2-way banks)

// ---- compile-time path tables ----
constexpr int kPL1[N_PATHS]  = {0,0,0,1,1,1,1,1,1,1,2,2,2,2,2,2,2,2,2};
constexpr int kPL2[N_PATHS]  = {0,1,2,0,1,1,1,2,2,2,0,1,1,1,2,2,2,2,2};
constexpr int kPL3[N_PATHS]  = {0,1,2,1,0,1,2,1,2,3,2,1,2,3,0,1,2,3,4};
constexpr int kIOFF[3]  = {0,1,4};
constexpr int kSP[5][6] = {{0,4,14,0,0,0},{1,3,5,7,11,15},{2,6,8,10,12,16},{9,13,17,0,0,0},{18,0,0,0,0,0}};
constexpr int kKS[5] = {3,6,6,3,1};
constexpr int kNT[5] = {4,4,4,2,1};
constexpr int kOB[5] = {0,64,256,576,800};
constexpr int kFB[5] = {0,12,36,60,66};
#define N_FRAGS 67

// ================= constexpr Wigner tables (r2-validated math) ==========
struct ccplx { double re, im; };
constexpr ccplx cmulc(ccplx a, ccplx b){ return {a.re*b.re - a.im*b.im, a.re*b.im + a.im*b.re}; }
constexpr double cfact(int n){ double f = 1.0; for (int i = 2; i <= n; ++i) f *= i; return f; }
constexpr double csqrt(double x){
  if (x <= 0.0) return 0.0;
  double g = x > 1.0 ? x : 1.0;
  for (int i = 0; i < 64; ++i) g = 0.5*(g + x/g);
  return g;
}
constexpr double c_su2cg(int j1,int j2,int j3,int m1,int m2){
  int m3 = m1+m2;
  int am3 = m3 < 0 ? -m3 : m3;
  int dj = j1-j2 < 0 ? j2-j1 : j1-j2;
  if (j3 < dj || j3 > j1+j2 || am3 > j3) return 0.0;
  double pref = (2.0*j3+1.0)*cfact(j3+j1-j2)*cfact(j3-j1+j2)*cfact(j1+j2-j3)/cfact(j1+j2+j3+1);
  pref = csqrt(pref);
  pref *= csqrt(cfact(j3+m3)*cfact(j3-m3)*cfact(j1-m1)*cfact(j1+m1)*cfact(j2-m2)*cfact(j2+m2));
  double s = 0.0;
  for (int k = 0; k <= j1+j2-j3; ++k){
    int a1=j1+j2-j3-k, a2=j1-m1-k, a3=j2+m2-k, a4=j3-j2+m1+k, a5=j3-j1-m2+k;
    if (a1<0||a2<0||a3<0||a4<0||a5<0) continue;
    double d = cfact(k)*cfact(a1)*cfact(a2)*cfact(a3)*cfact(a4)*cfact(a5);
    s += ((k&1) ? -1.0 : 1.0)/d;
  }
  return pref*s;
}
// q(l)[r][c] incl. (-i)^l rotation (l=1:-i, l=2:-1, l=3:+i)
constexpr ccplx qel(int l, int r, int c){
  const double rt = 0.70710678118654752440;
  int m = r - l;
  ccplx v{0.0, 0.0};
  if (m < 0){
    if (c == l - m) v = {rt, 0.0};
    else if (c == l + m) v = {0.0, -rt};
  } else if (m == 0){
    if (c == l) v = {1.0, 0.0};
  } else {
    double s = (m & 1) ? -1.0 : 1.0;
    if (c == l + m) v = {s*rt, 0.0};
    else if (c == l - m) v = {0.0, s*rt};
  }
  int ph = l & 3;
  if (ph == 1) return { v.im, -v.re};
  if (ph == 2) return {-v.re, -v.im};
  if (ph == 3) return {-v.im,  v.re};
  return v;
}
template<int P>
constexpr auto make_cg(){
  constexpr int l1 = kPL1[P], l2 = kPL2[P], l3 = kPL3[P];
  constexpr int D1 = 2*l1+1, D2v = 2*l2+1, D3 = 2*l3+1;
  double su[D1][D2v] = {};
  for (int i = 0; i < D1; ++i)
    for (int j = 0; j < D2v; ++j)
      su[i][j] = c_su2cg(l1, l2, l3, i-l1, j-l2);
  std::array<double, (size_t)D1*D2v*D3> re{}, im{};
  double sre = 0.0, sim = 0.0;
  for (int a = 0; a < D1; ++a)
    for (int b = 0; b < D2v; ++b)
      for (int c = 0; c < D3; ++c){
        ccplx acc{0.0, 0.0};
        for (int i = 0; i < D1; ++i)
          for (int j = 0; j < D2v; ++j){
            int kk = l3 + (i-l1) + (j-l2);
            if (kk < 0 || kk >= D3) continue;
            double cgv = su[i][j];
            if (cgv == 0.0) continue;
            ccplx q3 = qel(l3, c, kk);
            ccplx pr = cmulc(cmulc(qel(l1,a,i), qel(l2,b,j)), ccplx{q3.re, -q3.im});
            acc.re += pr.re*cgv; acc.im += pr.im*cgv;
          }
        size_t e = ((size_t)a*D2v + b)*D3 + c;
        re[e] = acc.re; im[e] = acc.im;
        sre += acc.re < 0 ? -acc.re : acc.re;
        sim += acc.im < 0 ? -acc.im : acc.im;
      }
  std::array<float, (size_t)D1*D2v*D3> out{};
  const bool useRe = (sre >= sim);
  const double norm = 1.0/csqrt((double)D3);
  for (size_t e = 0; e < out.size(); ++e){
    double v = (useRe ? re[e] : im[e])*norm;
    if (v < 1e-10 && v > -1e-10) v = 0.0;
    out[e] = (float)v;
  }
  return out;
}
template<int P> struct CGTab { static constexpr auto tab = make_cg<P>(); };
template<int P, int K> constexpr bool row_any(int E){
  for (int k = 0; k < K; ++k) if (CGTab<P>::tab[(size_t)E*K + k] != 0.0f) return true;
  return false;
}

__device__ inline unsigned short f2bf(float v){  // RNE fp32->bf16
  unsigned u = __builtin_bit_cast(unsigned, v);
  unsigned r = u + 0x7FFFu + ((u>>16)&1u);
  return (unsigned short)(r>>16);
}

// ---------------- W -> fragment-ordered bf16 (scale folded) ----------------
__global__ void prep_w_kernel(const float* __restrict__ W0, const float* __restrict__ W1,
                              const float* __restrict__ W2, const float* __restrict__ W3,
                              const float* __restrict__ W4, unsigned short* __restrict__ wout){
  int el = blockIdx.x*256 + threadIdx.x;
  if (el >= N_FRAGS*512) return;
  int frag = el>>9, r = el&511, lam = r>>3, j = r&7;
  int l  = (frag<12)?0 : (frag<36)?1 : (frag<60)?2 : (frag<66)?3 : 4;
  int fb = (l==0)?0 : (l==1)?12 : (l==2)?36 : (l==3)?60 : 66;
  int Ks = (l==0)?3 : (l==1)?6 : (l==2)?6 : (l==3)?3 : 1;
  int U  = (l==0)?96 : (l==1)?192 : (l==2)?192 : (l==3)?96 : 32;
  int rel = frag - fb, nt = rel/Ks, tt = rel - nt*Ks;
  int o = nt*16 + (lam&15);
  int u = tt*32 + (lam>>4)*8 + j;
  const float* W = (l==0)?W0 : (l==1)?W1 : (l==2)?W2 : (l==3)?W3 : W4;
  float scale = (l==0||l==3) ? 0.10206207261596575f
              : (l==4)       ? 0.17677669529663687f
                             : 0.07216878364870323f;
  wout[el] = f2bf(W[o*U + u] * scale);
}

// ---------------- main kernel ----------------
// Block = 128 thr = 2 waves, 16 samples staged once in LDS (fp16, r7-validated).
// wave0: groups {0,1,3}, wave1: {2,4}; no barriers after staging.
// tt-OUTER loop: only one K-slice of A-frags live (af[K]) -> low VGPR -> 3 waves/SIMD.
// D-frags stored DIRECTLY to global: per lane K contiguous floats per (sample,o);
// lines fully covered by adjacent lanes' back-to-back stores (no slab, no RFO holes).
// A-frag (m89-validated): lane(s=lane&15,g=lane>>4), elem j -> TP(sample s, mul g*8+j).

template<int P, int K, int E, int KK>
struct CKk {
  static __device__ __forceinline__ void run(float (&a0)[K], float (&a1)[K], float p0, float p1){
    constexpr float w = CGTab<P>::tab[(size_t)E*K + KK];
    if constexpr (w != 0.0f){
      a0[KK] = __builtin_fmaf(w, p0, a0[KK]);
      a1[KK] = __builtin_fmaf(w, p1, a1[KK]);
    }
    if constexpr (KK+1 < K) CKk<P,K,E,KK+1>::run(a0, a1, p0, p1);
  }
};

template<int P, int K, int D2v, int O1, int O2, int E, int NE>
struct CElem {
  static __device__ __forceinline__ void run(float (&a0)[K], float (&a1)[K],
                                             const float* xa, const float* xb){
    if constexpr (row_any<P,K>(E)){
      constexpr int i = E / D2v, jj = E - i*D2v;
      float p0 = xa[O1+i] * xb[O2+jj];
      float p1 = xa[9+O1+i] * xb[9+O2+jj];
      CKk<P,K,E,0>::run(a0, a1, p0, p1);
    }
    if constexpr (E+1 < NE) CElem<P,K,D2v,O1,O2,E+1,NE>::run(a0, a1, xa, xb);
  }
};

// load only the [O,O+D) spans (even + odd mul) of one 18-half chunk, aligned half2s
template<int O, int D>
__device__ __forceinline__ void load_span(float* x, const __half* p){
  #pragma unroll
  for (int h = (O & ~1); h < O + D; h += 2){
    __half2 v = *reinterpret_cast<const __half2*>(p + h);
    x[h] = __half2float(v.x); x[h+1] = __half2float(v.y);
  }
  #pragma unroll
  for (int h = ((9+O) & ~1); h < 9 + O + D; h += 2){
    __half2 v = *reinterpret_cast<const __half2*>(p + h);
    x[h] = __half2float(v.x); x[h+1] = __half2float(v.y);
  }
}

template<int L, int TT>
struct TT2 {
  static constexpr int P  = kSP[L][TT];
  static constexpr int L1 = kPL1[P], L2_ = kPL2[P];
  static constexpr int D1 = 2*L1+1, D2v = 2*L2_+1;
  static constexpr int O1 = kIOFF[L1], O2 = kIOFF[L2_];
  static constexpr int K = 2*L+1, Ks = kKS[L], Nt = kNT[L];
  static __device__ __forceinline__ void run(f32x4 (&acc)[kNT[L]][2*L+1],
                                             const __half* i1p, const __half* i2p,
                                             const short* wf){
    u32x4 af[K];
    #pragma unroll
    for (int jp=0; jp<4; ++jp){
      float xa[18], xb[18];
      load_span<O1,D1>(xa, i1p + jp*18);
      load_span<O2,D2v>(xb, i2p + jp*18);
      float a0[K], a1[K];
      #pragma unroll
      for (int k=0;k<K;++k){ a0[k]=0.f; a1[k]=0.f; }
      CElem<P,K,D2v,O1,O2,0,D1*D2v>::run(a0, a1, xa, xb);
      #pragma unroll
      for (int k=0;k<K;++k){
        unsigned pk;
        asm("v_cvt_pk_bf16_f32 %0, %1, %2" : "=v"(pk) : "v"(a0[k]), "v"(a1[k]));
        af[k][jp] = pk;        // lo16 = j even, hi16 = j odd
      }
    }
    #pragma unroll
    for (int nt=0; nt<Nt; ++nt){
      const short8 bf = *reinterpret_cast<const short8*>(wf + (nt*Ks+TT)*512);
      #pragma unroll
      for (int k=0;k<K;++k)
        acc[nt][k] = __builtin_amdgcn_mfma_f32_16x16x32_bf16(
                       __builtin_bit_cast(short8, af[k]), bf, acc[nt][k], 0, 0, 0);
    }
    if constexpr (TT+1 < Ks) TT2<L,TT+1>::run(acc, i1p, i2p, wf);
  }
};

template<int L>
__device__ __forceinline__ void do_group(const __half* __restrict__ i1p,
                                         const __half* __restrict__ i2p,
                                         const short* __restrict__ wfrag,
                                         float* __restrict__ out,
                                         int nrowb, int N, int lane){
  constexpr int K = 2*L+1, Nt = kNT[L];
  const int s = lane&15, g = lane>>4;
  f32x4 acc[Nt][K];
  #pragma unroll
  for (int nt=0;nt<Nt;++nt)
    #pragma unroll
    for (int k=0;k<K;++k) acc[nt][k] = (f32x4){0.f,0.f,0.f,0.f};

  const short* wf = wfrag + (size_t)kFB[L]*512 + (size_t)lane*8;
  TT2<L,0>::run(acc, i1p, i2p, wf);

  // direct stores: D-frag row = sample g*4+r, col o = nt*16+s  [m89 layout]
  #pragma unroll
  for (int r=0;r<4;++r){
    const int n = nrowb + g*4 + r;
    if (n < N){
      float* op = out + (size_t)n*944 + kOB[L] + s*K;
      #pragma unroll
      for (int nt=0;nt<Nt;++nt)
        #pragma unroll
        for (int k=0;k<K;++k)
          op[nt*16*K + k] = acc[nt][k][r];
    }
  }
}

__global__ __launch_bounds__(128, 3) void tp_main(
    const float* __restrict__ x1, const float* __restrict__ x2,
    const short* __restrict__ wfrag, float* __restrict__ out, int N)
{
  __shared__ __align__(16) __half in1h[16*HROW];
  __shared__ __align__(16) __half in2h[16*HROW];
  const int t = threadIdx.x, w = t>>6, lane = t&63;
  const int nb = blockIdx.x*16;

  // stage 16 samples as fp16 (float4 global -> half4 LDS)
  for (int idx = t; idx < 16*72; idx += 128){
    int row = idx/72, c4 = idx - row*72;
    int n = nb + row;
    float4 v1 = {0,0,0,0}, v2 = {0,0,0,0};
    if (n < N){
      v1 = reinterpret_cast<const float4*>(x1 + (size_t)n*288)[c4];
      v2 = reinterpret_cast<const float4*>(x2 + (size_t)n*288)[c4];
    }
    int b = row*HROW + c4*4;
    ushort4 u1, u2;
    u1.x = __half_as_ushort(__float2half_rn(v1.x)); u1.y = __half_as_ushort(__float2half_rn(v1.y));
    u1.z = __half_as_ushort(__float2half_rn(v1.z)); u1.w = __half_as_ushort(__float2half_rn(v1.w));
    u2.x = __half_as_ushort(__float2half_rn(v2.x)); u2.y = __half_as_ushort(__float2half_rn(v2.y));
    u2.z = __half_as_ushort(__float2half_rn(v2.z)); u2.w = __half_as_ushort(__float2half_rn(v2.w));
    *reinterpret_cast<ushort4*>(&in1h[b]) = u1;
    *reinterpret_cast<ushort4*>(&in2h[b]) = u2;
  }
  __syncthreads();

  const int s = lane&15, g = lane>>4;
  const __half* i1p = &in1h[s*HROW + g*72];
  const __half* i2p = &in2h[s*HROW + g*72];

  if (w == 0){
    do_group<0>(i1p, i2p, wfrag, out, nb, N, lane);
    do_group<1>(i1p, i2p, wfrag, out, nb, N, lane);
    do_group<3>(i1p, i2p, wfrag, out, nb, N, lane);
  } else {
    do_group<2>(i1p, i2p, wfrag, out, nb, N, lane);
    do_group<4>(i1p, i2p, wfrag, out, nb, N, lane);
  }
}

extern "C" void kernel_launch(void* const* d_in, const int* in_sizes, int n_in,
                              void* d_out, int out_size, void* d_ws, size_t ws_size,
                              hipStream_t stream)
{
  (void)n_in; (void)out_size; (void)ws_size;
  const float* x1 = (const float*)d_in[0];
  const float* x2 = (const float*)d_in[1];
  const float* W0 = (const float*)d_in[2];
  const float* W1 = (const float*)d_in[3];
  const float* W2 = (const float*)d_in[4];
  const float* W3 = (const float*)d_in[5];
  const float* W4 = (const float*)d_in[6];
  float* out = (float*)d_out;
  int N = in_sizes[0] / 288;

  prep_w_kernel<<<dim3((N_FRAGS*512 + 255)/256), dim3(256), 0, stream>>>(
      W0, W1, W2, W3, W4, (unsigned short*)d_ws);
  int grid = (N + 15) / 16;
  tp_main<<<dim3(grid), dim3(128), 0, stream>>>(
      x1, x2, (const short*)d_ws, out, N);
}

// Round 10
// 89.307 us; speedup vs baseline: 4.6054x; 4.2605x over previous
//
#include <hip/hip_runtime.h>
#include <hip/hip_fp16.h>
#include <array>

typedef __attribute__((ext_vector_type(8))) _Float16 f16x8;
typedef __attribute__((ext_vector_type(4))) float f32x4;
typedef __attribute__((ext_vector_type(4))) unsigned u32x4;

#define N_PATHS 19
#define SROW 148            // slab row stride (floats)
#define SROWH 298           // input LDS row stride in halves (149 dw, odd -> 16 distinct banks)

// ---- compile-time path tables ----
constexpr int kPL1[N_PATHS]  = {0,0,0,1,1,1,1,1,1,1,2,2,2,2,2,2,2,2,2};
constexpr int kPL2[N_PATHS]  = {0,1,2,0,1,1,1,2,2,2,0,1,1,1,2,2,2,2,2};
constexpr int kPL3[N_PATHS]  = {0,1,2,1,0,1,2,1,2,3,2,1,2,3,0,1,2,3,4};
constexpr int kIOFF[3]  = {0,1,4};
constexpr int kSP[5][6] = {{0,4,14,0,0,0},{1,3,5,7,11,15},{2,6,8,10,12,16},{9,13,17,0,0,0},{18,0,0,0,0,0}};
constexpr int kKS[5] = {3,6,6,3,1};
constexpr int kNT[5] = {4,4,4,2,1};
constexpr int kOB[5] = {0,64,256,576,800};
constexpr int kFB[5] = {0,12,36,60,66};
#define N_FRAGS 67

// ================= constexpr Wigner tables (r2-validated math) ==========
struct ccplx { double re, im; };
constexpr ccplx cmulc(ccplx a, ccplx b){ return {a.re*b.re - a.im*b.im, a.re*b.im + a.im*b.re}; }
constexpr double cfact(int n){ double f = 1.0; for (int i = 2; i <= n; ++i) f *= i; return f; }
constexpr double csqrt(double x){
  if (x <= 0.0) return 0.0;
  double g = x > 1.0 ? x : 1.0;
  for (int i = 0; i < 64; ++i) g = 0.5*(g + x/g);
  return g;
}
constexpr double c_su2cg(int j1,int j2,int j3,int m1,int m2){
  int m3 = m1+m2;
  int am3 = m3 < 0 ? -m3 : m3;
  int dj = j1-j2 < 0 ? j2-j1 : j1-j2;
  if (j3 < dj || j3 > j1+j2 || am3 > j3) return 0.0;
  double pref = (2.0*j3+1.0)*cfact(j3+j1-j2)*cfact(j3-j1+j2)*cfact(j1+j2-j3)/cfact(j1+j2+j3+1);
  pref = csqrt(pref);
  pref *= csqrt(cfact(j3+m3)*cfact(j3-m3)*cfact(j1-m1)*cfact(j1+m1)*cfact(j2-m2)*cfact(j2+m2));
  double s = 0.0;
  for (int k = 0; k <= j1+j2-j3; ++k){
    int a1=j1+j2-j3-k, a2=j1-m1-k, a3=j2+m2-k, a4=j3-j2+m1+k, a5=j3-j1-m2+k;
    if (a1<0||a2<0||a3<0||a4<0||a5<0) continue;
    double d = cfact(k)*cfact(a1)*cfact(a2)*cfact(a3)*cfact(a4)*cfact(a5);
    s += ((k&1) ? -1.0 : 1.0)/d;
  }
  return pref*s;
}
// q(l)[r][c] incl. (-i)^l rotation (l=1:-i, l=2:-1, l=3:+i)
constexpr ccplx qel(int l, int r, int c){
  const double rt = 0.70710678118654752440;
  int m = r - l;
  ccplx v{0.0, 0.0};
  if (m < 0){
    if (c == l - m) v = {rt, 0.0};
    else if (c == l + m) v = {0.0, -rt};
  } else if (m == 0){
    if (c == l) v = {1.0, 0.0};
  } else {
    double s = (m & 1) ? -1.0 : 1.0;
    if (c == l + m) v = {s*rt, 0.0};
    else if (c == l - m) v = {0.0, s*rt};
  }
  int ph = l & 3;
  if (ph == 1) return { v.im, -v.re};
  if (ph == 2) return {-v.re, -v.im};
  if (ph == 3) return {-v.im,  v.re};
  return v;
}
template<int P>
constexpr auto make_cg(){
  constexpr int l1 = kPL1[P], l2 = kPL2[P], l3 = kPL3[P];
  constexpr int D1 = 2*l1+1, D2v = 2*l2+1, D3 = 2*l3+1;
  double su[D1][D2v] = {};
  for (int i = 0; i < D1; ++i)
    for (int j = 0; j < D2v; ++j)
      su[i][j] = c_su2cg(l1, l2, l3, i-l1, j-l2);
  std::array<double, (size_t)D1*D2v*D3> re{}, im{};
  double sre = 0.0, sim = 0.0;
  for (int a = 0; a < D1; ++a)
    for (int b = 0; b < D2v; ++b)
      for (int c = 0; c < D3; ++c){
        ccplx acc{0.0, 0.0};
        for (int i = 0; i < D1; ++i)
          for (int j = 0; j < D2v; ++j){
            int kk = l3 + (i-l1) + (j-l2);
            if (kk < 0 || kk >= D3) continue;
            double cgv = su[i][j];
            if (cgv == 0.0) continue;
            ccplx q3 = qel(l3, c, kk);
            ccplx pr = cmulc(cmulc(qel(l1,a,i), qel(l2,b,j)), ccplx{q3.re, -q3.im});
            acc.re += pr.re*cgv; acc.im += pr.im*cgv;
          }
        size_t e = ((size_t)a*D2v + b)*D3 + c;
        re[e] = acc.re; im[e] = acc.im;
        sre += acc.re < 0 ? -acc.re : acc.re;
        sim += acc.im < 0 ? -acc.im : acc.im;
      }
  std::array<float, (size_t)D1*D2v*D3> out{};
  const bool useRe = (sre >= sim);
  const double norm = 1.0/csqrt((double)D3);
  for (size_t e = 0; e < out.size(); ++e){
    double v = (useRe ? re[e] : im[e])*norm;
    if (v < 1e-10 && v > -1e-10) v = 0.0;
    out[e] = (float)v;
  }
  return out;
}
template<int P> struct CGTab { static constexpr auto tab = make_cg<P>(); };
template<int P, int K> constexpr bool row_any(int E){
  for (int k = 0; k < K; ++k) if (CGTab<P>::tab[(size_t)E*K + k] != 0.0f) return true;
  return false;
}
// constexpr fp32 -> fp16 bits (RN; values are normal-range, no ties in practice)
constexpr unsigned short h_bits(double v){
  if (v == 0.0) return 0;
  unsigned short s = 0;
  if (v < 0){ s = 0x8000; v = -v; }
  int e = 0;
  while (v >= 2.0){ v *= 0.5; ++e; }
  while (v < 1.0){ v *= 2.0; --e; }
  double m = (v - 1.0) * 1024.0;
  int mi = (int)(m + 0.5);
  if (mi == 1024){ mi = 0; ++e; }
  return (unsigned short)(s | ((unsigned)(e + 15) << 10) | (unsigned)mi);
}
constexpr unsigned h2_bits(double v){
  unsigned short h = h_bits(v);
  return (unsigned)h | ((unsigned)h << 16);
}

// ---------------- W -> fragment-ordered fp16 (scale folded) ----------------
__global__ void prep_w_kernel(const float* __restrict__ W0, const float* __restrict__ W1,
                              const float* __restrict__ W2, const float* __restrict__ W3,
                              const float* __restrict__ W4, unsigned short* __restrict__ wout){
  int el = blockIdx.x*256 + threadIdx.x;
  if (el >= N_FRAGS*512) return;
  int frag = el>>9, r = el&511, lam = r>>3, j = r&7;
  int l  = (frag<12)?0 : (frag<36)?1 : (frag<60)?2 : (frag<66)?3 : 4;
  int fb = (l==0)?0 : (l==1)?12 : (l==2)?36 : (l==3)?60 : 66;
  int Ks = (l==0)?3 : (l==1)?6 : (l==2)?6 : (l==3)?3 : 1;
  int U  = (l==0)?96 : (l==1)?192 : (l==2)?192 : (l==3)?96 : 32;
  int rel = frag - fb, nt = rel/Ks, tt = rel - nt*Ks;
  int o = nt*16 + (lam&15);
  int u = tt*32 + (lam>>4)*8 + j;
  const float* W = (l==0)?W0 : (l==1)?W1 : (l==2)?W2 : (l==3)?W3 : W4;
  float scale = (l==0||l==3) ? 0.10206207261596575f
              : (l==4)       ? 0.17677669529663687f
                             : 0.07216878364870323f;
  wout[el] = __half_as_ushort(__float2half_rn(W[o*U + u] * scale));
}

// ---------------- main kernel ----------------
// Block = 128 thr = 2 waves, 16 samples; staged LDS layout TRANSPOSED to j-pairs:
// in[s][g][e][jp] = __half2(mul g*8+2jp, mul g*8+2jp+1) of element e.
// Build is packed fp16 (__hmul2/__hfma2, CG as packed-half immediates); the
// accumulator IS the A-frag pair. f16 MFMA + fp16 W. Slab + full-line flush (r7).
// A-frag (m89-validated): lane(s=lane&15,g=lane>>4), elem j -> TP(sample s, mul g*8+j).

template<int P, int K, int E, int KK>
struct PKk {
  static __device__ __forceinline__ void run(__half2 (&a)[K], __half2 p){
    constexpr float w = CGTab<P>::tab[(size_t)E*K + KK];
    if constexpr (w != 0.0f){
      constexpr unsigned W2 = h2_bits((double)w);
      a[KK] = __hfma2(__builtin_bit_cast(__half2, W2), p, a[KK]);
    }
    if constexpr (KK+1 < K) PKk<P,K,E,KK+1>::run(a, p);
  }
};

template<int P, int K, int D2v, int E, int NE>
struct PElem {
  static __device__ __forceinline__ void run(__half2 (&a)[K],
                                             const __half2* xa, const __half2* xb){
    if constexpr (row_any<P,K>(E)){
      constexpr int i = E / D2v, jj = E - i*D2v;
      __half2 p = __hmul2(xa[i], xb[jj]);
      PKk<P,K,E,0>::run(a, p);
    }
    if constexpr (E+1 < NE) PElem<P,K,D2v,E+1,NE>::run(a, xa, xb);
  }
};

template<int L, int TT>
struct TTF {
  static constexpr int P  = kSP[L][TT];
  static constexpr int L1 = kPL1[P], L2_ = kPL2[P];
  static constexpr int D1 = 2*L1+1, D2v = 2*L2_+1;
  static constexpr int O1 = kIOFF[L1], O2 = kIOFF[L2_];
  static constexpr int K = 2*L+1, Ks = kKS[L], Nt = kNT[L];
  static __device__ __forceinline__ void run(f32x4 (&acc)[kNT[L]][2*L+1],
                                             const __half* i1p, const __half* i2p,
                                             const short* wf){
    u32x4 af[K];
    #pragma unroll
    for (int jp=0; jp<4; ++jp){
      __half2 xa[D1], xb[D2v];
      #pragma unroll
      for (int i=0;i<D1;++i)
        xa[i] = *reinterpret_cast<const __half2*>(i1p + (O1+i)*8 + jp*2);
      #pragma unroll
      for (int j=0;j<D2v;++j)
        xb[j] = *reinterpret_cast<const __half2*>(i2p + (O2+j)*8 + jp*2);
      __half2 a[K];
      #pragma unroll
      for (int k=0;k<K;++k) a[k] = __builtin_bit_cast(__half2, 0u);
      PElem<P,K,D2v,0,D1*D2v>::run(a, xa, xb);
      #pragma unroll
      for (int k=0;k<K;++k) af[k][jp] = __builtin_bit_cast(unsigned, a[k]);
    }
    #pragma unroll
    for (int nt=0; nt<Nt; ++nt){
      const f16x8 bf = *reinterpret_cast<const f16x8*>(wf + (nt*Ks+TT)*512);
      #pragma unroll
      for (int k=0;k<K;++k)
        acc[nt][k] = __builtin_amdgcn_mfma_f32_16x16x32_f16(
                       __builtin_bit_cast(f16x8, af[k]), bf, acc[nt][k], 0, 0, 0);
    }
    if constexpr (TT+1 < Ks) TTF<L,TT+1>::run(acc, i1p, i2p, wf);
  }
};

template<int L>
__device__ __forceinline__ void do_group(const __half* __restrict__ i1p,
                                         const __half* __restrict__ i2p,
                                         const short* __restrict__ wfrag,
                                         float* slab, float* __restrict__ out,
                                         int nrowb, int N, int lane){
  constexpr int K = 2*L+1, Nt = kNT[L];
  const int s = lane&15, g = lane>>4;
  f32x4 acc[Nt][K];
  #pragma unroll
  for (int nt=0;nt<Nt;++nt)
    #pragma unroll
    for (int k=0;k<K;++k) acc[nt][k] = (f32x4){0.f,0.f,0.f,0.f};

  const short* wf = wfrag + (size_t)kFB[L]*512 + (size_t)lane*8;
  TTF<L,0>::run(acc, i1p, i2p, wf);

  // per-nt slab stage + full-line flush (r7-validated write path)
  #pragma unroll
  for (int nt=0; nt<Nt; ++nt){
    #pragma unroll
    for (int k=0;k<K;++k)
      #pragma unroll
      for (int r=0;r<4;++r)
        slab[(g*4+r)*SROW + s*K + k] = acc[nt][k][r];   // D-frag row = sample g*4+r [m89]
    const int rr = lane>>2, q4 = lane&3;
    const float* sp = slab + rr*SROW;
    const bool on = (nrowb + rr) < N;
    float* op = out + (size_t)(nrowb+rr)*944 + kOB[L] + nt*16*K;
    #pragma unroll
    for (int c=0;c<K;++c){
      float4 v = *reinterpret_cast<const float4*>(sp + (c*4+q4)*4);
      if (on) *reinterpret_cast<float4*>(op + (c*4+q4)*4) = v;
    }
  }
}

__global__ __launch_bounds__(128, 2) void tp_main(
    const float* __restrict__ x1, const float* __restrict__ x2,
    const short* __restrict__ wfrag, float* __restrict__ out, int N)
{
  __shared__ __align__(16) __half in1h[16*SROWH];
  __shared__ __align__(16) __half in2h[16*SROWH];
  __shared__ __align__(16) float stage[2*16*SROW];
  const int t = threadIdx.x, w = t>>6, lane = t&63;
  const int nb = blockIdx.x*16;

  // stage 16 samples as fp16, transposed to [g][e][jp] pair layout
  for (int idx = t; idx < 16*72; idx += 128){
    int row = idx/72, c4 = idx - row*72;
    int n = nb + row;
    float4 v1 = {0,0,0,0}, v2 = {0,0,0,0};
    if (n < N){
      v1 = reinterpret_cast<const float4*>(x1 + (size_t)n*288)[c4];
      v2 = reinterpret_cast<const float4*>(x2 + (size_t)n*288)[c4];
    }
    float a1v[4] = {v1.x, v1.y, v1.z, v1.w};
    float a2v[4] = {v2.x, v2.y, v2.z, v2.w};
    #pragma unroll
    for (int u=0; u<4; ++u){
      int c = c4*4 + u;
      int m = c/9, e = c - m*9;
      int g = m>>3, j = m&7;
      int haddr = row*SROWH + g*72 + e*8 + j;   // j = jp*2+o laid out contiguously
      in1h[haddr] = __float2half_rn(a1v[u]);
      in2h[haddr] = __float2half_rn(a2v[u]);
    }
  }
  __syncthreads();

  const int s = lane&15, g = lane>>4;
  const __half* i1p = &in1h[s*SROWH + g*72];
  const __half* i2p = &in2h[s*SROWH + g*72];
  float* slab = &stage[w*16*SROW];

  if (w == 0){
    do_group<0>(i1p, i2p, wfrag, slab, out, nb, N, lane);
    do_group<1>(i1p, i2p, wfrag, slab, out, nb, N, lane);
    do_group<3>(i1p, i2p, wfrag, slab, out, nb, N, lane);
  } else {
    do_group<2>(i1p, i2p, wfrag, slab, out, nb, N, lane);
    do_group<4>(i1p, i2p, wfrag, slab, out, nb, N, lane);
  }
}

extern "C" void kernel_launch(void* const* d_in, const int* in_sizes, int n_in,
                              void* d_out, int out_size, void* d_ws, size_t ws_size,
                              hipStream_t stream)
{
  (void)n_in; (void)out_size; (void)ws_size;
  const float* x1 = (const float*)d_in[0];
  const float* x2 = (const float*)d_in[1];
  const float* W0 = (const float*)d_in[2];
  const float* W1 = (const float*)d_in[3];
  const float* W2 = (const float*)d_in[4];
  const float* W3 = (const float*)d_in[5];
  const float* W4 = (const float*)d_in[6];
  float* out = (float*)d_out;
  int N = in_sizes[0] / 288;

  prep_w_kernel<<<dim3((N_FRAGS*512 + 255)/256), dim3(256), 0, stream>>>(
      W0, W1, W2, W3, W4, (unsigned short*)d_ws);
  int grid = (N + 15) / 16;
  tp_main<<<dim3(grid), dim3(128), 0, stream>>>(
      x1, x2, (const short*)d_ws, out, N);
}